// Round 7
// baseline (230.370 us; speedup 1.0000x reference)
//
#include <hip/hip_runtime.h>

#define D 64
#define TILE 1024
#define RB 8               // dst ranges == XCD count
#define EPB 2048           // edges per chunk in hist/fill
#define EPT 8              // edges per thread (256 thr * 8 = 2048)

__device__ __forceinline__ float rlane(float v, int l) {
    return __int_as_float(__builtin_amdgcn_readlane(__float_as_int(v), l));
}

// ---------------------------------------------------------------------------
// Phase 1a: deg[dst]++ — range-partitioned (block residue r handles dst range
// r) with ballot-compaction: matching dsts are compacted into LDS so the
// atomic phase runs with full 64-lane waves instead of ~1/8 masked lanes.
// ---------------------------------------------------------------------------
__global__ __launch_bounds__(256) void hist_kernel(
    const int* __restrict__ edge_dst, int* __restrict__ deg,
    int n_edges, int n_nodes)
{
    __shared__ int s_cnt;
    __shared__ int s_d[EPB];
    int r = blockIdx.x & (RB - 1);
    int chunk = blockIdx.x >> 3;
    int lo = (int)((long long)r * n_nodes / RB);
    int hi = (int)((long long)(r + 1) * n_nodes / RB);
    if (threadIdx.x == 0) s_cnt = 0;
    __syncthreads();

    int base = chunk * EPB + threadIdx.x * EPT;
    int d[EPT];
    if (base + EPT - 1 < n_edges) {
        int4 v0 = *(const int4*)(edge_dst + base);
        int4 v1 = *(const int4*)(edge_dst + base + 4);
        d[0]=v0.x; d[1]=v0.y; d[2]=v0.z; d[3]=v0.w;
        d[4]=v1.x; d[5]=v1.y; d[6]=v1.z; d[7]=v1.w;
    } else {
        #pragma unroll
        for (int k = 0; k < EPT; ++k)
            d[k] = (base + k < n_edges) ? edge_dst[base + k] : -1;
    }

    int lane = threadIdx.x & 63;
    unsigned long long lt = (lane == 63) ? ~0ull >> 1
                                         : ((1ull << (lane + 1)) - 1) >> 1;
    #pragma unroll
    for (int k = 0; k < EPT; ++k) {
        bool m = (d[k] >= lo && d[k] < hi);
        unsigned long long bal = __ballot(m);
        int cw = __popcll(bal);
        if (cw) {
            int bs = 0;
            if (lane == 0) bs = atomicAdd(&s_cnt, cw);
            bs = __builtin_amdgcn_readfirstlane(bs);
            if (m) s_d[bs + __popcll(bal & lt)] = d[k];
        }
    }
    __syncthreads();
    int c = s_cnt;
    for (int i = threadIdx.x; i < c; i += 256) atomicAdd(&deg[s_d[i]], 1);
}

// ---------------------------------------------------------------------------
// Phase 1b-i: per-tile (1024 elems) sums. int4 loads, shfl reduce.
// ---------------------------------------------------------------------------
__global__ __launch_bounds__(256) void tile_sum_kernel(
    const int* __restrict__ deg, int* __restrict__ partial, int n)
{
    int t = threadIdx.x;
    int base = blockIdx.x * TILE + t * 4;
    int s = 0;
    if (base + 3 < n) {
        int4 v = *(const int4*)(deg + base);
        s = v.x + v.y + v.z + v.w;
    } else {
        for (int k = 0; k < 4; ++k) if (base + k < n) s += deg[base + k];
    }
    #pragma unroll
    for (int off = 1; off < 64; off <<= 1) s += __shfl_xor(s, off, 64);
    __shared__ int wsum[4];
    int lane = t & 63, wv = t >> 6;
    if (lane == 0) wsum[wv] = s;
    __syncthreads();
    if (t == 0) partial[blockIdx.x] = wsum[0] + wsum[1] + wsum[2] + wsum[3];
}

// ---------------------------------------------------------------------------
// Phase 1b-ii: exclusive scan of tile partials (1 block, 64 lanes).
// ---------------------------------------------------------------------------
__global__ __launch_bounds__(64) void scan_partial_kernel(
    const int* __restrict__ partial, int* __restrict__ ppref, int nb,
    int* __restrict__ offsets, int n, int n_edges)
{
    int lane = threadIdx.x;
    int carry = 0;
    for (int base = 0; base < nb; base += 64) {
        int idx = base + lane;
        int v = (idx < nb) ? partial[idx] : 0;
        int inc = v;
        #pragma unroll
        for (int off = 1; off < 64; off <<= 1) {
            int u = __shfl_up(inc, off, 64);
            if (lane >= off) inc += u;
        }
        if (idx < nb) ppref[idx] = carry + inc - v;
        carry += __shfl(inc, 63, 64);
    }
    if (lane == 0) offsets[n] = n_edges;
}

// ---------------------------------------------------------------------------
// Phase 1b-iii: per-tile scan -> offsets + cursor.
// ---------------------------------------------------------------------------
__global__ __launch_bounds__(256) void scan_tile_kernel(
    const int* __restrict__ deg, const int* __restrict__ ppref,
    int* __restrict__ offsets, int* __restrict__ cursor, int n)
{
    int t = threadIdx.x;
    int base = blockIdx.x * TILE + t * 4;
    int e0 = 0, e1 = 0, e2 = 0, e3 = 0;
    if (base + 3 < n) {
        int4 v = *(const int4*)(deg + base);
        e0 = v.x; e1 = v.y; e2 = v.z; e3 = v.w;
    } else {
        if (base + 0 < n) e0 = deg[base + 0];
        if (base + 1 < n) e1 = deg[base + 1];
        if (base + 2 < n) e2 = deg[base + 2];
        if (base + 3 < n) e3 = deg[base + 3];
    }
    int s = e0 + e1 + e2 + e3;
    int inc = s;
    int lane = t & 63, wv = t >> 6;
    #pragma unroll
    for (int off = 1; off < 64; off <<= 1) {
        int u = __shfl_up(inc, off, 64);
        if (lane >= off) inc += u;
    }
    __shared__ int wsum[4];
    if (lane == 63) wsum[wv] = inc;
    __syncthreads();
    int wpre = 0;
    for (int wq = 0; wq < wv; ++wq) wpre += wsum[wq];
    int excl = ppref[blockIdx.x] + wpre + inc - s;
    int o0 = excl, o1 = o0 + e0, o2 = o1 + e1, o3 = o2 + e2;
    if (base + 0 < n) { offsets[base + 0] = o0; cursor[base + 0] = o0; }
    if (base + 1 < n) { offsets[base + 1] = o1; cursor[base + 1] = o1; }
    if (base + 2 < n) { offsets[base + 2] = o2; cursor[base + 2] = o2; }
    if (base + 3 < n) { offsets[base + 3] = o3; cursor[base + 3] = o3; }
}

// ---------------------------------------------------------------------------
// Phase 1c: CSR fill, range-partitioned + ballot-compaction. Phase 2 runs
// cursor atomics + csr stores with full lanes; src/w fetched by compacted
// edge index (within the chunk's 8KB window -> cache-hot).
// ---------------------------------------------------------------------------
__global__ __launch_bounds__(256) void fill_kernel(
    const int* __restrict__ edge_src, const int* __restrict__ edge_dst,
    const float* __restrict__ edge_weight,
    int* __restrict__ cursor, int2* __restrict__ csr_sw,
    int n_edges, int n_nodes)
{
    __shared__ int s_cnt;
    __shared__ int s_d[EPB];
    __shared__ int s_e[EPB];
    int r = blockIdx.x & (RB - 1);
    int chunk = blockIdx.x >> 3;
    int lo = (int)((long long)r * n_nodes / RB);
    int hi = (int)((long long)(r + 1) * n_nodes / RB);
    if (threadIdx.x == 0) s_cnt = 0;
    __syncthreads();

    int base = chunk * EPB + threadIdx.x * EPT;
    int d[EPT];
    if (base + EPT - 1 < n_edges) {
        int4 v0 = *(const int4*)(edge_dst + base);
        int4 v1 = *(const int4*)(edge_dst + base + 4);
        d[0]=v0.x; d[1]=v0.y; d[2]=v0.z; d[3]=v0.w;
        d[4]=v1.x; d[5]=v1.y; d[6]=v1.z; d[7]=v1.w;
    } else {
        #pragma unroll
        for (int k = 0; k < EPT; ++k)
            d[k] = (base + k < n_edges) ? edge_dst[base + k] : -1;
    }

    int lane = threadIdx.x & 63;
    unsigned long long lt = (lane == 63) ? ~0ull >> 1
                                         : ((1ull << (lane + 1)) - 1) >> 1;
    #pragma unroll
    for (int k = 0; k < EPT; ++k) {
        bool m = (d[k] >= lo && d[k] < hi);
        unsigned long long bal = __ballot(m);
        int cw = __popcll(bal);
        if (cw) {
            int bs = 0;
            if (lane == 0) bs = atomicAdd(&s_cnt, cw);
            bs = __builtin_amdgcn_readfirstlane(bs);
            if (m) {
                int p = bs + __popcll(bal & lt);
                s_d[p] = d[k];
                s_e[p] = base + k;
            }
        }
    }
    __syncthreads();
    int c = s_cnt;
    for (int i = threadIdx.x; i < c; i += 256) {
        int dk = s_d[i];
        int e  = s_e[i];
        int pos = atomicAdd(&cursor[dk], 1);
        csr_sw[pos] = make_int2(edge_src[e], __float_as_int(edge_weight[e]));
    }
}

// ---------------------------------------------------------------------------
// Phase 2: wave-per-node gather, 8-deep ILP. csr reads wave-uniform (s_load);
// feature rows 256B-coalesced.
// ---------------------------------------------------------------------------
__global__ __launch_bounds__(256) void gather_kernel(
    const float* __restrict__ features, const int2* __restrict__ csr_sw,
    const int* __restrict__ offsets, float* __restrict__ neighbor, int n_nodes)
{
    int lane = threadIdx.x & 63;
    int gw = (blockIdx.x * 256 + threadIdx.x) >> 6;
    int nw = (gridDim.x * 256) >> 6;
    for (int i = gw; i < n_nodes; i += nw) {
        int beg = __builtin_amdgcn_readfirstlane(offsets[i]);
        int end = __builtin_amdgcn_readfirstlane(offsets[i + 1]);
        float acc = 0.f;
        int j = beg;
        for (; j + 7 < end; j += 8) {
            int2 p[8];
            float a[8];
            #pragma unroll
            for (int q = 0; q < 8; ++q) p[q] = csr_sw[j + q];
            #pragma unroll
            for (int q = 0; q < 8; ++q)
                a[q] = features[(size_t)p[q].x * D + lane];
            #pragma unroll
            for (int q = 0; q < 8; ++q)
                acc = fmaf(__int_as_float(p[q].y), a[q], acc);
        }
        for (; j < end; ++j) {
            int2 p = csr_sw[j];
            acc = fmaf(__int_as_float(p.y), features[(size_t)p.x * D + lane], acc);
        }
        neighbor[(size_t)i * D + lane] = acc;
    }
}

// ---------------------------------------------------------------------------
// Phase 3: out = normalize([features | neighbor] @ W^T + b)
// Lane o holds W row o in VGPRs. FOUR independent fma chains (32-deep each)
// fill the 4-cycle fma latency even at modest occupancy.
// ---------------------------------------------------------------------------
__global__ __launch_bounds__(256) void gemm_norm_kernel(
    const float* __restrict__ features, const float* __restrict__ neighbor,
    const float* __restrict__ W, const float* __restrict__ bias,
    float* __restrict__ out, int n_nodes)
{
    int lane = threadIdx.x & 63;
    float wr[128];
    const float4* Wv = (const float4*)(W + (size_t)lane * 128);
    #pragma unroll
    for (int q = 0; q < 32; ++q) {
        float4 v = Wv[q];
        wr[4 * q + 0] = v.x; wr[4 * q + 1] = v.y;
        wr[4 * q + 2] = v.z; wr[4 * q + 3] = v.w;
    }
    float bl = bias[lane];

    int gw = (blockIdx.x * 256 + threadIdx.x) >> 6;
    int nw = (gridDim.x * 256) >> 6;
    for (int i = gw; i < n_nodes; i += nw) {
        float cf = features[(size_t)i * D + lane];
        float cn = neighbor[(size_t)i * D + lane];
        float a0 = bl, a1 = 0.f, a2 = 0.f, a3 = 0.f;
        #pragma unroll
        for (int k = 0; k < 32; ++k) {
            a0 = fmaf(rlane(cf, k),      wr[k],      a0);
            a1 = fmaf(rlane(cf, k + 32), wr[k + 32], a1);
            a2 = fmaf(rlane(cn, k),      wr[k + 64], a2);
            a3 = fmaf(rlane(cn, k + 32), wr[k + 96], a3);
        }
        float acc = (a0 + a1) + (a2 + a3);
        float s = acc * acc;
        #pragma unroll
        for (int m = 1; m < 64; m <<= 1) s += __shfl_xor(s, m, 64);
        out[(size_t)i * D + lane] = acc / fmaxf(sqrtf(s), 1e-12f);
    }
}

extern "C" void kernel_launch(void* const* d_in, const int* in_sizes, int n_in,
                              void* d_out, int out_size, void* d_ws, size_t ws_size,
                              hipStream_t stream) {
    const float* features    = (const float*)d_in[0];
    const int*   edge_src    = (const int*)d_in[1];
    const int*   edge_dst    = (const int*)d_in[2];
    const float* edge_weight = (const float*)d_in[3];
    const float* W           = (const float*)d_in[4];
    const float* b           = (const float*)d_in[5];
    float*       out         = (float*)d_out;

    int n = in_sizes[0] / D;
    int E = in_sizes[1];
    int nb = (n + TILE - 1) / TILE;
    int nchunks = (E + EPB - 1) / EPB;

    // workspace layout (256B-aligned slabs)
    char* ws = (char*)d_ws;
    auto al = [](size_t x) { return (x + 255) & ~(size_t)255; };
    size_t o = 0;
    int* deg      = (int*)(ws + o); o += al((size_t)n * 4);
    int* cursor   = (int*)(ws + o); o += al((size_t)n * 4);
    int* offsets  = (int*)(ws + o); o += al((size_t)(n + 1) * 4);
    int* partial  = (int*)(ws + o); o += al((size_t)nb * 4);
    int* ppref    = (int*)(ws + o); o += al((size_t)nb * 4);
    int2* csr_sw  = (int2*)(ws + o); o += al((size_t)E * 8);
    float* neighbor = (float*)(ws + o);

    hipMemsetAsync(deg, 0, (size_t)n * 4, stream);

    hist_kernel<<<nchunks * RB, 256, 0, stream>>>(edge_dst, deg, E, n);
    tile_sum_kernel<<<nb, 256, 0, stream>>>(deg, partial, n);
    scan_partial_kernel<<<1, 64, 0, stream>>>(partial, ppref, nb, offsets, n, E);
    scan_tile_kernel<<<nb, 256, 0, stream>>>(deg, ppref, offsets, cursor, n);
    fill_kernel<<<nchunks * RB, 256, 0, stream>>>(edge_src, edge_dst, edge_weight,
                                                  cursor, csr_sw, E, n);
    gather_kernel<<<2048, 256, 0, stream>>>(features, csr_sw, offsets,
                                            neighbor, n);
    gemm_norm_kernel<<<2048, 256, 0, stream>>>(features, neighbor, W, b, out, n);
}